// Round 4
// baseline (16800.414 us; speedup 1.0000x reference)
//
#include <hip/hip_runtime.h>

#define BB 16
#define NN 1024
#define HH 1024

__device__ __forceinline__ float wave_reduce_sum(float v) {
#pragma unroll
    for (int off = 32; off > 0; off >>= 1) v += __shfl_down(v, off, 64);
    return v;
}

// monotone map f32 -> u32 (order-preserving over all finite floats)
__device__ __forceinline__ unsigned int fkey(float f) {
    unsigned int u = __float_as_uint(f);
    return u ^ ((u >> 31) ? 0xFFFFFFFFu : 0x80000000u);
}

// init packed argmax buffer: key=0 (loses to any real candidate), idx decodes to 0
__global__ __launch_bounds__(256) void init_packed_kernel(unsigned long long* __restrict__ p) {
    const int t = blockIdx.x * 256 + threadIdx.x;
    if (t < 2 * BB * NN) p[t] = 1023ull;
}

// ---------------------------------------------------------------------------
// Phase 1: masked row-argmax of gram matrix G = attn*attn^T per (dir,b).
// argmax_j A == argmax over valid j (opi[j]!=0, j!=i) of dot(attn_i, attn_j).
// 1024 blocks = 2 dir x 16 b x 16 i-tile x 2 j-half (4 blocks/CU).
// Double-buffered LDS, 1 barrier/chunk, prefetch regs during compute (T14).
// B tile stored row-major with kblk XOR (j>>3) swizzle: conflict-free b128
// writes AND reads. Cross-block merge via packed u64 atomicMax.
// ---------------------------------------------------------------------------
__global__ __launch_bounds__(256, 4) void gram_argmax_kernel(
    const float* __restrict__ attn0, const float* __restrict__ attn1,
    const int* __restrict__ opi0, const int* __restrict__ opi1,
    unsigned long long* __restrict__ packed)
{
    // XCD-pinning swizzle: group g=(dir,b) -> XCD g&7; inner 32 blocks contiguous
    const int bid = blockIdx.x;
    const int g = (bid & 7) + ((bid >> 8) << 3);   // 0..31
    const int inner = (bid >> 3) & 31;             // 0..31
    const int dir = g >> 4;
    const int b = g & 15;
    const int i0 = (inner >> 1) << 6;
    const int jh = inner & 1;

    const float* __restrict__ base = (dir ? attn1 : attn0) + (size_t)b * NN * HH;
    const int* __restrict__ opi = (dir ? opi1 : opi0) + b * NN;

    const int tid = threadIdx.x;
    const int tx = tid & 15, ty = tid >> 4;
    const int lrow = tid >> 3;   // 0..31
    const int lkq = tid & 7;     // 0..7

    union SMem {
        struct { float A[2][64][36]; float B[2][64][36]; } t;   // 36864 B
        struct { float rv[64][16]; int ri[64][16]; } r;
    };
    __shared__ SMem sm;

    float4 rA0, rA1, rB0, rB1;
    const int swz0 = (lkq ^ ((lrow >> 3) & 7)) << 2;          // lrow in 0..31
    const int swz1 = (lkq ^ (((lrow + 32) >> 3) & 7)) << 2;   // lrow+32

    auto stage_load = [&](int jt, int kc) {
        const int k0 = kc << 5;
        const float* pa = base + (size_t)(i0 + lrow) * HH + k0 + (lkq << 2);
        rA0 = *(const float4*)pa;
        rA1 = *(const float4*)(pa + (size_t)32 * HH);
        const float* pb = base + (size_t)((jt << 6) + lrow) * HH + k0 + (lkq << 2);
        rB0 = *(const float4*)pb;
        rB1 = *(const float4*)(pb + (size_t)32 * HH);
    };
    auto stage_write = [&](int buf) {
        *(float4*)&sm.t.A[buf][lrow][lkq << 2] = rA0;
        *(float4*)&sm.t.A[buf][lrow + 32][lkq << 2] = rA1;
        *(float4*)&sm.t.B[buf][lrow][swz0] = rB0;
        *(float4*)&sm.t.B[buf][lrow + 32][swz1] = rB1;
    };

    float bestv[4];
    int besti[4];
#pragma unroll
    for (int q = 0; q < 4; ++q) { bestv[q] = -3.402823466e38f; besti[q] = 0; }

    const int jtbeg = jh * 8, jtend = jtbeg + 8;
    int cur = 0;
    stage_load(jtbeg, 0);
    stage_write(0);
    __syncthreads();

    const int swb = tx >> 1;   // == (4*tx+p)>>3 for p in 0..3

    for (int jt = jtbeg; jt < jtend; ++jt) {
        float acc[4][4];
#pragma unroll
        for (int q = 0; q < 4; ++q)
#pragma unroll
            for (int p = 0; p < 4; ++p) acc[q][p] = 0.f;

        for (int kc = 0; kc < 32; ++kc) {
            const bool hasnext = !(jt == jtend - 1 && kc == 31);
            if (hasnext) {
                if (kc < 31) stage_load(jt, kc + 1);
                else stage_load(jt + 1, 0);
            }
#pragma unroll
            for (int k4 = 0; k4 < 8; ++k4) {
                const int kb = (k4 ^ swb) << 2;
                const float4 A0 = *(const float4*)&sm.t.A[cur][(ty << 2) + 0][k4 << 2];
                const float4 A1 = *(const float4*)&sm.t.A[cur][(ty << 2) + 1][k4 << 2];
                const float4 A2 = *(const float4*)&sm.t.A[cur][(ty << 2) + 2][k4 << 2];
                const float4 A3 = *(const float4*)&sm.t.A[cur][(ty << 2) + 3][k4 << 2];
                const float4 B0 = *(const float4*)&sm.t.B[cur][(tx << 2) + 0][kb];
                const float4 B1 = *(const float4*)&sm.t.B[cur][(tx << 2) + 1][kb];
                const float4 B2 = *(const float4*)&sm.t.B[cur][(tx << 2) + 2][kb];
                const float4 B3 = *(const float4*)&sm.t.B[cur][(tx << 2) + 3][kb];
#define DOT4(q, p, Aq, Bp) \
                acc[q][p] = fmaf(Aq.x, Bp.x, acc[q][p]); \
                acc[q][p] = fmaf(Aq.y, Bp.y, acc[q][p]); \
                acc[q][p] = fmaf(Aq.z, Bp.z, acc[q][p]); \
                acc[q][p] = fmaf(Aq.w, Bp.w, acc[q][p]);
                DOT4(0, 0, A0, B0) DOT4(0, 1, A0, B1) DOT4(0, 2, A0, B2) DOT4(0, 3, A0, B3)
                DOT4(1, 0, A1, B0) DOT4(1, 1, A1, B1) DOT4(1, 2, A1, B2) DOT4(1, 3, A1, B3)
                DOT4(2, 0, A2, B0) DOT4(2, 1, A2, B1) DOT4(2, 2, A2, B2) DOT4(2, 3, A2, B3)
                DOT4(3, 0, A3, B0) DOT4(3, 1, A3, B1) DOT4(3, 2, A3, B2) DOT4(3, 3, A3, B3)
#undef DOT4
            }
            if (hasnext) stage_write(cur ^ 1);
            __syncthreads();
            cur ^= 1;
        }
        // masked running argmax; ascending j + strict > keeps first-index max
        const int j0 = jt << 6;
#pragma unroll
        for (int p = 0; p < 4; ++p) {
            const int j = j0 + (tx << 2) + p;
            const bool jv = (opi[j] != 0);
#pragma unroll
            for (int q = 0; q < 4; ++q) {
                const int i = i0 + (ty << 2) + q;
                const float v = acc[q][p];
                if (jv && (j != i) && (v > bestv[q])) { bestv[q] = v; besti[q] = j; }
            }
        }
    }

    // final in-loop barrier already passed; tile LDS is dead -> reuse for reduce
#pragma unroll
    for (int q = 0; q < 4; ++q) { sm.r.rv[(ty << 2) + q][tx] = bestv[q]; sm.r.ri[(ty << 2) + q][tx] = besti[q]; }
    __syncthreads();
    if (tid < 64) {
        float bv = sm.r.rv[tid][0];
        int bi = sm.r.ri[tid][0];
#pragma unroll
        for (int t = 1; t < 16; ++t) {
            const float v = sm.r.rv[tid][t];
            const int ix = sm.r.ri[tid][t];
            if (v > bv || (v == bv && ix < bi)) { bv = v; bi = ix; }
        }
        const unsigned long long pk =
            ((unsigned long long)fkey(bv) << 32) | (unsigned long long)(1023 - bi);
        atomicMax(&packed[(size_t)(dir * BB + b) * NN + i0 + tid], pk);
    }
}

// ---------------------------------------------------------------------------
// Phase 2: gather matched opinion row, 3 logits/direction, combine, labels.
// ---------------------------------------------------------------------------
__global__ __launch_bounds__(256) void logits_kernel(
    const float* __restrict__ a2o_asp, const float* __restrict__ a2o_opi,
    const float* __restrict__ o2a_asp, const float* __restrict__ o2a_opi,
    const int* __restrict__ mA, const int* __restrict__ mO,
    const float* __restrict__ W_A, const float* __restrict__ bias_A,
    const float* __restrict__ W_O, const float* __restrict__ bias_O,
    const unsigned long long* __restrict__ packed, float* __restrict__ out)
{
    const int row = blockIdx.x;          // b*N + i
    const int b = row >> 10;
    const int tid = threadIdx.x;
    const int idxA = 1023 - (int)(packed[row] & 0xFFFFFFFFu);
    const int idxO = 1023 - (int)(packed[BB * NN + row] & 0xFFFFFFFFu);

    const float* aA = a2o_asp + (size_t)row * HH;
    const float* gA = a2o_opi + ((size_t)(b << 10) + idxA) * HH;
    const float* aO = o2a_asp + (size_t)row * HH;
    const float* gO = o2a_opi + ((size_t)(b << 10) + idxO) * HH;

    const int h = tid * 4;
    const float4 va = *(const float4*)(aA + h);
    const float4 vg = *(const float4*)(gA + h);
    const float4 ua = *(const float4*)(aO + h);
    const float4 ug = *(const float4*)(gO + h);

    float acc[6];
#pragma unroll
    for (int c = 0; c < 3; ++c) {
        acc[c] = va.x * W_A[(h+0)*3+c] + va.y * W_A[(h+1)*3+c]
               + va.z * W_A[(h+2)*3+c] + va.w * W_A[(h+3)*3+c]
               + vg.x * W_A[(HH+h+0)*3+c] + vg.y * W_A[(HH+h+1)*3+c]
               + vg.z * W_A[(HH+h+2)*3+c] + vg.w * W_A[(HH+h+3)*3+c];
        acc[3+c] = ua.x * W_O[(h+0)*3+c] + ua.y * W_O[(h+1)*3+c]
                 + ua.z * W_O[(h+2)*3+c] + ua.w * W_O[(h+3)*3+c]
                 + ug.x * W_O[(HH+h+0)*3+c] + ug.y * W_O[(HH+h+1)*3+c]
                 + ug.z * W_O[(HH+h+2)*3+c] + ug.w * W_O[(HH+h+3)*3+c];
    }

    __shared__ float red[4][6];
    const int lane = tid & 63, wv = tid >> 6;
#pragma unroll
    for (int c = 0; c < 6; ++c) {
        const float v = wave_reduce_sum(acc[c]);
        if (lane == 0) red[wv][c] = v;
    }
    __syncthreads();
    if (tid == 0) {
        const int mAv = mA[row], mOv = mO[row];
        float fl[3];
#pragma unroll
        for (int c = 0; c < 3; ++c) {
            const float sA = red[0][c] + red[1][c] + red[2][c] + red[3][c];
            const float sO = red[0][3+c] + red[1][3+c] + red[2][3+c] + red[3][3+c];
            const float lA = mAv ? (sA + bias_A[c]) : 0.f;
            const float lO = mOv ? (sO + bias_O[c]) : 0.f;
            fl[c] = 0.5f * (lA + lO);
            out[BB*NN + row*3 + c] = fl[c];
        }
        int lab = -1;
        if (mAv + mOv > 0) {
            lab = 0;
            if (fl[1] > fl[0]) lab = 1;
            if (fl[2] > fl[lab]) lab = 2;
        }
        out[row] = (float)lab;
    }
}

// ---------------------------------------------------------------------------
// Phase 3: weighted CE, mean per sentence, summed over batch.
// ---------------------------------------------------------------------------
__global__ __launch_bounds__(256) void loss_kernel(
    const int* __restrict__ mA, const int* __restrict__ mO,
    const int* __restrict__ sent, float* __restrict__ out)
{
    const int tid = threadIdx.x;
    const int lane = tid & 63, wv = tid >> 6;
    __shared__ float rn[4], rd[4];
    float loss = 0.f;
    for (int b = 0; b < BB; ++b) {
        float num = 0.f, den = 0.f;
        for (int i = tid; i < NN; i += 256) {
            const int row = (b << 10) + i;
            const float l0 = out[BB*NN + row*3 + 0];
            const float l1 = out[BB*NN + row*3 + 1];
            const float l2 = out[BB*NN + row*3 + 2];
            const int s = sent[row];
            const bool valid = (mA[row] + mO[row]) > 0;
            const float m = fmaxf(l0, fmaxf(l1, l2));
            const float lse = m + logf(expf(l0 - m) + expf(l1 - m) + expf(l2 - m));
            const float li = (s == 0) ? l0 : ((s == 1) ? l1 : l2);
            const float w = ((s == 0) ? 1.f : ((s == 1) ? 2.f : 4.f)) * (valid ? 1.f : 0.f);
            num += w * (lse - li);
            den += w;
        }
        num = wave_reduce_sum(num);
        den = wave_reduce_sum(den);
        if (lane == 0) { rn[wv] = num; rd[wv] = den; }
        __syncthreads();
        if (tid == 0) {
            const float nn = rn[0] + rn[1] + rn[2] + rn[3];
            const float dd = rd[0] + rd[1] + rd[2] + rd[3];
            loss += (dd > 0.f) ? nn / dd : 0.f;
        }
        __syncthreads();
    }
    if (tid == 0) out[BB*NN + BB*NN*3] = loss;  // out[65536]
}

extern "C" void kernel_launch(void* const* d_in, const int* in_sizes, int n_in,
                              void* d_out, int out_size, void* d_ws, size_t ws_size,
                              hipStream_t stream) {
    const float* a2o_asp = (const float*)d_in[0];
    const float* a2o_opi = (const float*)d_in[1];
    const float* o2a_asp = (const float*)d_in[2];
    const float* o2a_opi = (const float*)d_in[3];
    const int* m_asp_A = (const int*)d_in[4];
    const int* m_opi_A = (const int*)d_in[5];
    const int* m_asp_O = (const int*)d_in[6];
    const int* m_opi_O = (const int*)d_in[7];
    const int* sent    = (const int*)d_in[8];
    const float* W_A = (const float*)d_in[9];
    const float* b_A = (const float*)d_in[10];
    const float* W_O = (const float*)d_in[11];
    const float* b_O = (const float*)d_in[12];
    float* out = (float*)d_out;
    unsigned long long* packed = (unsigned long long*)d_ws;   // [2][B][N] u64 = 256 KiB

    init_packed_kernel<<<128, 256, 0, stream>>>(packed);
    // dir0 (A2O) attends with A2O_aspect_h; dir1 (O2A) with O2A_opinion_h
    gram_argmax_kernel<<<1024, 256, 0, stream>>>(a2o_asp, o2a_opi, m_opi_A, m_opi_O, packed);
    logits_kernel<<<BB * NN, 256, 0, stream>>>(a2o_asp, a2o_opi, o2a_asp, o2a_opi,
                                               m_asp_A, m_asp_O, W_A, b_A, W_O, b_O,
                                               packed, out);
    loss_kernel<<<1, 256, 0, stream>>>(m_asp_A, m_asp_O, sent, out);
}

// Round 14
// 1914.283 us; speedup vs baseline: 8.7763x; 8.7763x over previous
//
#include <hip/hip_runtime.h>

#define BB 16
#define NN 1024
#define HH 1024

__device__ __forceinline__ float wave_reduce_sum(float v) {
#pragma unroll
    for (int off = 32; off > 0; off >>= 1) v += __shfl_down(v, off, 64);
    return v;
}

// monotone map f32 -> u32 (order-preserving over all finite floats)
__device__ __forceinline__ unsigned int fkey(float f) {
    unsigned int u = __float_as_uint(f);
    return u ^ ((u >> 31) ? 0xFFFFFFFFu : 0x80000000u);
}

// init packed argmax buffer: key=0 loses to any candidate; idx decodes to 0
__global__ __launch_bounds__(256) void init_packed_kernel(unsigned long long* __restrict__ p) {
    const int t = blockIdx.x * 256 + threadIdx.x;
    if (t < 2 * BB * NN) p[t] = 1023ull;
}

// ---------------------------------------------------------------------------
// Phase 1: masked row-argmax of G = attn*attn^T per (dir,b).
// 2048 blocks = 2 dir x 16 b x 8 i-tile x 8 j-tile; 128x128 tile, BK=16.
// 8x8 microtile (1 FMA per LDS byte -> LDS-BW balanced with FMA rate).
// Reg-staged double buffer (T14): global loads issued before the FMA block
// (latency hidden under ~1024 FMAs), ds_write after, 1 barrier/chunk.
// NO min-waves launch bound (round 4's forced 64-VGPR spill lesson).
// LDS [row][16] linear; k-quad XOR swizzle (quad ^= (row>>3)&3) applied on
// the GLOBAL source address and on reads: involution, so reads reconstruct
// the true row; all LDS reads <=2-way bank-aliased (free), writes contiguous.
// Per-wave lanes 8x8 (ag rows x bg cols). Cross-block merge: packed atomicMax.
// ---------------------------------------------------------------------------
__global__ __launch_bounds__(256) void gram_argmax_kernel(
    const float* __restrict__ attn0, const float* __restrict__ attn1,
    const int* __restrict__ opi0, const int* __restrict__ opi1,
    unsigned long long* __restrict__ packed)
{
    // XCD pinning: group g=(dir,b) fixed per XCD slot; 64 inner blocks contiguous
    const int bid = blockIdx.x;
    const int g = (bid & 7) | (((bid >> 9) & 3) << 3);   // 0..31
    const int inner = (bid >> 3) & 63;                    // 0..63
    const int dir = g >> 4, b = g & 15;
    const int i0 = ((inner >> 3) & 7) << 7;
    const int j0 = (inner & 7) << 7;

    const float* __restrict__ base = (dir ? attn1 : attn0) + (size_t)b * NN * HH;
    const int* __restrict__ opi = (dir ? opi1 : opi0) + b * NN;

    const int tid = threadIdx.x;
    const int w = tid >> 6, l = tid & 63;
    const int ag = ((w & 1) << 3) | (l >> 3);        // 0..15: A row-group
    const int bg = (((w >> 1) & 1) << 3) | (l & 7);  // 0..15: B col-group

    __shared__ union SM {
        float t[2][2][2048];                              // [buf][A/B][128*16]
        struct { float rv[128][16]; int ri[128][16]; } r; // argmax reduce
    } sm;

    // staging: thread tid owns flat floats [tid*4..+3] of each 64-row half
    // (row = tid>>2, quad = tid&3); source k-quad pre-swizzled
    const int i_row = tid >> 2;
    const int quad = tid & 3;
    const int swq = (quad ^ ((i_row >> 3) & 3)) << 2;
    const size_t arow0 = (size_t)(i0 + i_row) * HH + swq;
    const size_t arow1 = arow0 + (size_t)64 * HH;
    const size_t brow0 = (size_t)(j0 + i_row) * HH + swq;
    const size_t brow1 = brow0 + (size_t)64 * HH;

    float4 stA0, stA1, stB0, stB1;
    auto gload = [&](int kc) {
        const int k0 = kc << 4;
        stA0 = *(const float4*)(base + arow0 + k0);
        stA1 = *(const float4*)(base + arow1 + k0);
        stB0 = *(const float4*)(base + brow0 + k0);
        stB1 = *(const float4*)(base + brow1 + k0);
    };
    auto ldst = [&](int bf) {
        *(float4*)&sm.t[bf][0][tid * 4]        = stA0;
        *(float4*)&sm.t[bf][0][1024 + tid * 4] = stA1;
        *(float4*)&sm.t[bf][1][tid * 4]        = stB0;
        *(float4*)&sm.t[bf][1][1024 + tid * 4] = stB1;
    };

    float acc[8][8];
#pragma unroll
    for (int m = 0; m < 8; ++m)
#pragma unroll
        for (int p = 0; p < 8; ++p) acc[m][p] = 0.f;

    gload(0); ldst(0);
    __syncthreads();

    int bf = 0;
    for (int c = 0; c < 64; ++c) {
        if (c < 63) gload(c + 1);   // in flight across the FMA block
        const float* At = sm.t[bf][0];
        const float* Bt = sm.t[bf][1];
#pragma unroll
        for (int k4 = 0; k4 < 4; ++k4) {
            const int ka = (k4 ^ (ag & 3)) << 2;
            const int kb = (k4 ^ (bg & 3)) << 2;
            float4 af[8];
#pragma unroll
            for (int m = 0; m < 8; ++m)
                af[m] = *(const float4*)&At[(((ag << 3) + m) << 4) + ka];
#pragma unroll
            for (int p = 0; p < 8; ++p) {
                const float4 bv = *(const float4*)&Bt[(((bg << 3) + p) << 4) + kb];
#pragma unroll
                for (int m = 0; m < 8; ++m) {
                    acc[m][p] = fmaf(af[m].x, bv.x, acc[m][p]);
                    acc[m][p] = fmaf(af[m].y, bv.y, acc[m][p]);
                    acc[m][p] = fmaf(af[m].z, bv.z, acc[m][p]);
                    acc[m][p] = fmaf(af[m].w, bv.w, acc[m][p]);
                }
            }
        }
        if (c < 63) ldst(bf ^ 1);   // write-late; vmcnt waits land here
        __syncthreads();
        bf ^= 1;
    }

    // per-thread masked argmax over its 8x8; ascending j + strict > = first-max
#pragma unroll
    for (int m = 0; m < 8; ++m) {
        const int i = i0 + (ag << 3) + m;
        float bv = -3.402823466e38f; int bi = 0;
#pragma unroll
        for (int p = 0; p < 8; ++p) {
            const int j = j0 + (bg << 3) + p;
            const float v = acc[m][p];
            if ((opi[j] != 0) && (j != i) && (v > bv)) { bv = v; bi = j; }
        }
        sm.r.rv[(ag << 3) + m][bg] = bv;
        sm.r.ri[(ag << 3) + m][bg] = bi;
    }
    __syncthreads();
    if (tid < 128) {
        float bv = sm.r.rv[tid][0]; int bi = sm.r.ri[tid][0];
#pragma unroll
        for (int t = 1; t < 16; ++t) {
            const float v = sm.r.rv[tid][t]; const int ix = sm.r.ri[tid][t];
            if (v > bv || (v == bv && ix < bi)) { bv = v; bi = ix; }
        }
        const unsigned long long pk =
            ((unsigned long long)fkey(bv) << 32) | (unsigned long long)(1023 - bi);
        atomicMax(&packed[(size_t)(dir * BB + b) * NN + i0 + tid], pk);
    }
}

// ---------------------------------------------------------------------------
// Phase 2: gather matched opinion row, 3 logits/direction, combine, labels.
// ---------------------------------------------------------------------------
__global__ __launch_bounds__(256) void logits_kernel(
    const float* __restrict__ a2o_asp, const float* __restrict__ a2o_opi,
    const float* __restrict__ o2a_asp, const float* __restrict__ o2a_opi,
    const int* __restrict__ mA, const int* __restrict__ mO,
    const float* __restrict__ W_A, const float* __restrict__ bias_A,
    const float* __restrict__ W_O, const float* __restrict__ bias_O,
    const unsigned long long* __restrict__ packed, float* __restrict__ out)
{
    const int row = blockIdx.x;          // b*N + i
    const int b = row >> 10;
    const int tid = threadIdx.x;
    const int idxA = 1023 - (int)(packed[row] & 0xFFFFFFFFu);
    const int idxO = 1023 - (int)(packed[BB * NN + row] & 0xFFFFFFFFu);

    const float* aA = a2o_asp + (size_t)row * HH;
    const float* gA = a2o_opi + ((size_t)(b << 10) + idxA) * HH;
    const float* aO = o2a_asp + (size_t)row * HH;
    const float* gO = o2a_opi + ((size_t)(b << 10) + idxO) * HH;

    const int h = tid * 4;
    const float4 va = *(const float4*)(aA + h);
    const float4 vg = *(const float4*)(gA + h);
    const float4 ua = *(const float4*)(aO + h);
    const float4 ug = *(const float4*)(gO + h);

    float acc[6];
#pragma unroll
    for (int c = 0; c < 3; ++c) {
        acc[c] = va.x * W_A[(h+0)*3+c] + va.y * W_A[(h+1)*3+c]
               + va.z * W_A[(h+2)*3+c] + va.w * W_A[(h+3)*3+c]
               + vg.x * W_A[(HH+h+0)*3+c] + vg.y * W_A[(HH+h+1)*3+c]
               + vg.z * W_A[(HH+h+2)*3+c] + vg.w * W_A[(HH+h+3)*3+c];
        acc[3+c] = ua.x * W_O[(h+0)*3+c] + ua.y * W_O[(h+1)*3+c]
                 + ua.z * W_O[(h+2)*3+c] + ua.w * W_O[(h+3)*3+c]
                 + ug.x * W_O[(HH+h+0)*3+c] + ug.y * W_O[(HH+h+1)*3+c]
                 + ug.z * W_O[(HH+h+2)*3+c] + ug.w * W_O[(HH+h+3)*3+c];
    }

    __shared__ float red[4][6];
    const int lane = tid & 63, wv = tid >> 6;
#pragma unroll
    for (int c = 0; c < 6; ++c) {
        const float v = wave_reduce_sum(acc[c]);
        if (lane == 0) red[wv][c] = v;
    }
    __syncthreads();
    if (tid == 0) {
        const int mAv = mA[row], mOv = mO[row];
        float fl[3];
#pragma unroll
        for (int c = 0; c < 3; ++c) {
            const float sA = red[0][c] + red[1][c] + red[2][c] + red[3][c];
            const float sO = red[0][3+c] + red[1][3+c] + red[2][3+c] + red[3][3+c];
            const float lA = mAv ? (sA + bias_A[c]) : 0.f;
            const float lO = mOv ? (sO + bias_O[c]) : 0.f;
            fl[c] = 0.5f * (lA + lO);
            out[BB*NN + row*3 + c] = fl[c];
        }
        int lab = -1;
        if (mAv + mOv > 0) {
            lab = 0;
            if (fl[1] > fl[0]) lab = 1;
            if (fl[2] > fl[lab]) lab = 2;
        }
        out[row] = (float)lab;
    }
}

// ---------------------------------------------------------------------------
// Phase 3: weighted CE, mean per sentence, summed over batch.
// ---------------------------------------------------------------------------
__global__ __launch_bounds__(256) void loss_kernel(
    const int* __restrict__ mA, const int* __restrict__ mO,
    const int* __restrict__ sent, float* __restrict__ out)
{
    const int tid = threadIdx.x;
    const int lane = tid & 63, wv = tid >> 6;
    __shared__ float rn[4], rd[4];
    float loss = 0.f;
    for (int b = 0; b < BB; ++b) {
        float num = 0.f, den = 0.f;
        for (int i = tid; i < NN; i += 256) {
            const int row = (b << 10) + i;
            const float l0 = out[BB*NN + row*3 + 0];
            const float l1 = out[BB*NN + row*3 + 1];
            const float l2 = out[BB*NN + row*3 + 2];
            const int s = sent[row];
            const bool valid = (mA[row] + mO[row]) > 0;
            const float m = fmaxf(l0, fmaxf(l1, l2));
            const float lse = m + logf(expf(l0 - m) + expf(l1 - m) + expf(l2 - m));
            const float li = (s == 0) ? l0 : ((s == 1) ? l1 : l2);
            const float w = ((s == 0) ? 1.f : ((s == 1) ? 2.f : 4.f)) * (valid ? 1.f : 0.f);
            num += w * (lse - li);
            den += w;
        }
        num = wave_reduce_sum(num);
        den = wave_reduce_sum(den);
        if (lane == 0) { rn[wv] = num; rd[wv] = den; }
        __syncthreads();
        if (tid == 0) {
            const float nn = rn[0] + rn[1] + rn[2] + rn[3];
            const float dd = rd[0] + rd[1] + rd[2] + rd[3];
            loss += (dd > 0.f) ? nn / dd : 0.f;
        }
        __syncthreads();
    }
    if (tid == 0) out[BB*NN + BB*NN*3] = loss;  // out[65536]
}

extern "C" void kernel_launch(void* const* d_in, const int* in_sizes, int n_in,
                              void* d_out, int out_size, void* d_ws, size_t ws_size,
                              hipStream_t stream) {
    const float* a2o_asp = (const float*)d_in[0];
    const float* a2o_opi = (const float*)d_in[1];
    const float* o2a_asp = (const float*)d_in[2];
    const float* o2a_opi = (const float*)d_in[3];
    const int* m_asp_A = (const int*)d_in[4];
    const int* m_opi_A = (const int*)d_in[5];
    const int* m_asp_O = (const int*)d_in[6];
    const int* m_opi_O = (const int*)d_in[7];
    const int* sent    = (const int*)d_in[8];
    const float* W_A = (const float*)d_in[9];
    const float* b_A = (const float*)d_in[10];
    const float* W_O = (const float*)d_in[11];
    const float* b_O = (const float*)d_in[12];
    float* out = (float*)d_out;
    unsigned long long* packed = (unsigned long long*)d_ws;   // [2][B][N] u64

    init_packed_kernel<<<128, 256, 0, stream>>>(packed);
    // dir0 (A2O) attends with A2O_aspect_h; dir1 (O2A) with O2A_opinion_h
    gram_argmax_kernel<<<2048, 256, 0, stream>>>(a2o_asp, o2a_opi, m_opi_A, m_opi_O, packed);
    logits_kernel<<<BB * NN, 256, 0, stream>>>(a2o_asp, a2o_opi, o2a_asp, o2a_opi,
                                               m_asp_A, m_asp_O, W_A, b_A, W_O, b_O,
                                               packed, out);
    loss_kernel<<<1, 256, 0, stream>>>(m_asp_A, m_asp_O, sent, out);
}